// Round 7
// baseline (148.164 us; speedup 1.0000x reference)
//
#include <hip/hip_runtime.h>
#include <math.h>

#define THREADS 256
#define GAMMA 0.99

typedef float vf4 __attribute__((ext_vector_type(4)));   // native vector for nontemporal store

// ---------- padded LDS index: stride PT+1 per thread (odd) -> 2-way banks (free) ----------
template<int LPT>
__device__ __forceinline__ int padi(int i) { return i + (i >> LPT); }

// ---------- block-wide exclusive scan of linear transforms x -> g*x + v ----------
template<int NW>
__device__ __forceinline__ void block_compose_excl(int tid, double g, double v,
                                                   double& eg, double& ev,
                                                   double* lg, double* lv) {
    const int lane = tid & 63, wave = tid >> 6;
    double ig = g, iv = v;
#pragma unroll
    for (int k = 1; k < 64; k <<= 1) {
        double og = __shfl_up(ig, k);
        double ov = __shfl_up(iv, k);
        if (lane >= k) { iv = fma(ig, ov, iv); ig *= og; }
    }
    double weg = __shfl_up(ig, 1);
    double wev = __shfl_up(iv, 1);
    if (lane == 0) { weg = 1.0; wev = 0.0; }
    if (lane == 63) { lg[wave] = ig; lv[wave] = iv; }
    __syncthreads();
    double bg = 1.0, bv = 0.0;
    for (int w = 0; w < wave; ++w) { bv = fma(lg[w], bv, lv[w]); bg *= lg[w]; }
    eg = weg * bg;
    ev = fma(weg, bv, wev);
}

// ---------- block-wide exclusive additive scan of a pair ----------
template<int NW>
__device__ __forceinline__ void block_add_excl2(int tid, double a, double b,
                                                double& ea, double& eb,
                                                double* la, double* lb) {
    const int lane = tid & 63, wave = tid >> 6;
    double ia = a, ib = b;
#pragma unroll
    for (int k = 1; k < 64; k <<= 1) {
        double oa = __shfl_up(ia, k);
        double ob = __shfl_up(ib, k);
        if (lane >= k) { ia += oa; ib += ob; }
    }
    double wea = __shfl_up(ia, 1);
    double web = __shfl_up(ib, 1);
    if (lane == 0) { wea = 0.0; web = 0.0; }
    if (lane == 63) { la[wave] = ia; lb[wave] = ib; }
    __syncthreads();
    double ba = 0.0, bb = 0.0;
    for (int w = 0; w < wave; ++w) { ba += la[w]; bb += lb[w]; }
    ea = wea + ba;
    eb = web + bb;
}

// ---------- Phase 1+2 fused: per-chunk aggregates; LAST block scans chunk carries ----------
// agg[c*4 + {A,Ps,Pq,P2}], car[c*3 + {Rin,S1C,S2C}]
template<int PT, int LPT, int LOG2CH>
__global__ __launch_bounds__(THREADS) void rs_phase12(const float* __restrict__ in,
                                                      double* __restrict__ agg,
                                                      double* __restrict__ car,
                                                      int* __restrict__ counter, int nchunk) {
    constexpr int CHUNKE = THREADS * PT;
    __shared__ double lg[4], lv[4], r1[4], r2[4], r3[4], la[4], lb[4];
    __shared__ int is_last;
    const int tid = threadIdx.x, lane = tid & 63, wave = tid >> 6;
    const int chunk = blockIdx.x;
    const float* src = in + (size_t)chunk * CHUNKE + (size_t)tid * PT;

    float rv[PT];
#pragma unroll
    for (int q = 0; q < PT / 4; ++q) {
        const float4 t = ((const float4*)src)[q];
        rv[4 * q] = t.x; rv[4 * q + 1] = t.y; rv[4 * q + 2] = t.z; rv[4 * q + 3] = t.w;
    }
    const float gf = (float)GAMMA;
    float p = 0.f, psum = 0.f, pq = 0.f, p2 = 0.f, gp = 1.f;
#pragma unroll
    for (int j = 0; j < PT; ++j) {
        p = fmaf(gf, p, rv[j]);
        gp *= gf;
        psum += p;
        pq = fmaf(gp, p, pq);
        p2 = fmaf(p, p, p2);
    }
    const double g = GAMMA;
    double gPT = g;
#pragma unroll
    for (int e = 0; e < LPT; ++e) gPT *= gPT;   // g^PT

    double eg, ev;
    block_compose_excl<4>(tid, gPT, (double)p, eg, ev, lg, lv);
    const double rho = ev, gexc = eg;

    const double G1 = g * (1.0 - gPT) / (1.0 - g);
    const double G2 = g * g * (1.0 - gPT * gPT) / (1.0 - g * g);
    double c1 = fma(rho, G1, (double)psum);
    double c2 = gexc * fma(rho, G2, (double)pq);
    double c3 = fma(rho * rho, G2, fma(2.0 * rho, (double)pq, (double)p2));
#pragma unroll
    for (int k = 32; k > 0; k >>= 1) {
        c1 += __shfl_down(c1, k);
        c2 += __shfl_down(c2, k);
        c3 += __shfl_down(c3, k);
    }
    if (lane == 0) { r1[wave] = c1; r2[wave] = c2; r3[wave] = c3; }
    __syncthreads();
    if (tid == 0) {
        double A = 0.0;
#pragma unroll
        for (int w = 0; w < 4; ++w) A = fma(lg[w], A, lv[w]);
        agg[4 * (size_t)chunk + 0] = A;
        agg[4 * (size_t)chunk + 1] = r1[0] + r1[1] + r1[2] + r1[3];
        agg[4 * (size_t)chunk + 2] = r2[0] + r2[1] + r2[2] + r2[3];
        agg[4 * (size_t)chunk + 3] = r3[0] + r3[1] + r3[2] + r3[3];
        __threadfence();                                   // release agg to device scope
        const int prev = atomicAdd(counter, 1);            // device-scope by default
        is_last = (prev == nchunk - 1) ? 1 : 0;
    }
    __syncthreads();
    if (!is_last) return;

    // ===== last arriving block: scan the chunk carries (streaming 3-pass) =====
    __threadfence();                                       // acquire all agg writes
    double gC = g;
#pragma unroll
    for (int e = 0; e < LOG2CH; ++e) gC *= gC;             // g^CHUNKE
    const double G1C = g * (1.0 - gC) / (1.0 - g);
    const double G2C = g * g * (1.0 - gC * gC) / (1.0 - g * g);

    const int CPT2 = (nchunk + THREADS - 1) / THREADS;
    const int b_lo = tid * CPT2;
    const int b_hi = min(nchunk, b_lo + CPT2);

    // pass 1: serial compose of own chunks (running pair only)
    double mg = 1.0, mv = 0.0;
    for (int c = b_lo; c < b_hi; ++c) { mv = fma(gC, mv, agg[4 * (size_t)c]); mg *= gC; }
    double eg2, ev2;
    block_compose_excl<4>(tid, mg, mv, eg2, ev2, lg, lv);

    // pass 2: running totals of s1/s2 (agg now L2-warm)
    double Rin = ev2, ts1 = 0.0, ts2 = 0.0;
    for (int c = b_lo; c < b_hi; ++c) {
        const double Ac = agg[4 * (size_t)c + 0];
        const double Ps = agg[4 * (size_t)c + 1];
        const double Pq = agg[4 * (size_t)c + 2];
        const double P2 = agg[4 * (size_t)c + 3];
        ts1 += fma(Rin, G1C, Ps);
        ts2 += fma(Rin * Rin, G2C, fma(2.0 * Rin, Pq, P2));
        Rin = fma(gC, Rin, Ac);
    }
    double ea, eb;
    block_add_excl2<4>(tid, ts1, ts2, ea, eb, la, lb);

    // pass 3: re-walk, write per-chunk carries
    Rin = ev2;
    for (int c = b_lo; c < b_hi; ++c) {
        const double Ac = agg[4 * (size_t)c + 0];
        const double Ps = agg[4 * (size_t)c + 1];
        const double Pq = agg[4 * (size_t)c + 2];
        const double P2 = agg[4 * (size_t)c + 3];
        car[3 * (size_t)c + 0] = Rin;
        car[3 * (size_t)c + 1] = ea;
        car[3 * (size_t)c + 2] = eb;
        ea += fma(Rin, G1C, Ps);
        eb += fma(Rin * Rin, G2C, fma(2.0 * Rin, Pq, P2));
        Rin = fma(gC, Rin, Ac);
    }
}

// ---------- Phase 3: rebase with true carries, emit scaled rewards (unchanged) ----------
template<int PT, int LPT>
__global__ __launch_bounds__(THREADS) void rs_phase3(const float* __restrict__ in,
                                                     float* __restrict__ out,
                                                     const double* __restrict__ car, int nchunk) {
    constexpr int CHUNKE = THREADS * PT;
    __shared__ float sbuf[CHUNKE + THREADS];
    __shared__ double lg[4], lv[4], la[4], lb[4];
    const int tid = threadIdx.x;
    const int chunk = blockIdx.x;
    const float* src = in + (size_t)chunk * CHUNKE + (size_t)tid * PT;

    float rv[PT];
#pragma unroll
    for (int q = 0; q < PT / 4; ++q) {
        const float4 t = ((const float4*)src)[q];
        rv[4 * q] = t.x; rv[4 * q + 1] = t.y; rv[4 * q + 2] = t.z; rv[4 * q + 3] = t.w;
    }
    const float gf = (float)GAMMA;
    float p = 0.f, psum = 0.f, pq = 0.f, p2 = 0.f, gp = 1.f;
#pragma unroll
    for (int j = 0; j < PT; ++j) {
        p = fmaf(gf, p, rv[j]);
        gp *= gf;
        psum += p;
        pq = fmaf(gp, p, pq);
        p2 = fmaf(p, p, p2);
    }
    const double g = GAMMA;
    double gPT = g;
#pragma unroll
    for (int e = 0; e < LPT; ++e) gPT *= gPT;

    double eg, ev;
    block_compose_excl<4>(tid, gPT, (double)p, eg, ev, lg, lv);

    const double RinC = car[3 * (size_t)chunk + 0];
    const double S1C  = car[3 * (size_t)chunk + 1];
    const double S2C  = car[3 * (size_t)chunk + 2];
    const double rin  = fma(eg, RinC, ev);      // true incoming R for this thread's segment

    const double G1 = g * (1.0 - gPT) / (1.0 - g);
    const double G2 = g * g * (1.0 - gPT * gPT) / (1.0 - g * g);
    const double s1 = fma(rin, G1, (double)psum);
    const double s2 = fma(rin * rin, G2, fma(2.0 * rin, (double)pq, (double)p2));
    double ea, eb;
    block_add_excl2<4>(tid, s1, s2, ea, eb, la, lb);
    const double S1b = S1C + ea;
    const double S2b = S2C + eb;

    const int a0 = padi<LPT>(tid * PT);          // = tid*(PT+1)

    if (chunk == 0) {
        // precise f64 epilogue for the small-cnt region (cancellation-sensitive)
        double R = rin, S1 = S1b, S2 = S2b;
        const size_t gbase = (size_t)tid * PT;
        for (int j = 0; j < PT; ++j) {
            const float rf = rv[j];
            R = fma(g, R, (double)rf);
            S1 += R;
            S2 = fma(R, R, S2);
            float ov;
            if (gbase + j == 0) {
                ov = rf;                         // cnt < 2 -> std = 1
            } else {
                const double cnt = (double)(gbase + j + 1);
                const double inv = 1.0 / cnt;
                const double mean = S1 * inv;
                double var = fma(S2, inv, -(mean * mean));
                var = var > 0.0 ? var : 0.0;
                double sd = sqrt(var);
                sd = sd > 1e-8 ? sd : 1e-8;
                ov = (float)((double)rf / sd);
            }
            sbuf[a0 + j] = ov;
        }
    } else {
        // cnt >= CHUNKE+1: var*cnt^2 = S2*cnt - S1^2 has no cancellation ->
        // out = rf * cnt * rsqrt(S2*cnt - S1^2). One v_rsq replaces 2 divs + sqrt.
        float R = (float)rin;
        float ls1 = 0.f, ls2 = 0.f;
        const float S1bf = (float)S1b, S2bf = (float)S2b;
        const float base_cnt = (float)((size_t)chunk * CHUNKE + (size_t)tid * PT);
#pragma unroll
        for (int j = 0; j < PT; ++j) {
            const float rf = rv[j];
            R = fmaf(gf, R, rf);
            ls1 += R;
            ls2 = fmaf(R, R, ls2);
            const float cnt = base_cnt + (float)(j + 1);
            const float S1f = S1bf + ls1;
            const float S2f = S2bf + ls2;
            float t = fmaf(S2f, cnt, -(S1f * S1f));
            t = fmaxf(t, 1e-12f);
            sbuf[a0 + j] = rf * cnt * __builtin_amdgcn_rsqf(t);
        }
    }
    __syncthreads();

    float* dst = out + (size_t)chunk * CHUNKE;
    for (int i = tid * 4; i < CHUNKE; i += THREADS * 4) {
        const int pp = padi<LPT>(i);
        vf4 v;
        v.x = sbuf[pp]; v.y = sbuf[pp + 1]; v.z = sbuf[pp + 2]; v.w = sbuf[pp + 3];
        __builtin_nontemporal_store(v, (vf4*)(dst + i));   // don't evict L3-resident input
    }
}

extern "C" void kernel_launch(void* const* d_in, const int* in_sizes, int n_in,
                              void* d_out, int out_size, void* d_ws, size_t ws_size,
                              hipStream_t stream) {
    (void)n_in; (void)out_size;
    const float* in = (const float*)d_in[0];
    float* out = (float*)d_out;
    double* ws = (double*)d_ws;
    const int n = in_sizes[0];

    const int nc = n / 4096;
    if ((n % 4096) == 0 && nc >= 1 && nc <= 4096 &&
        ws_size >= (size_t)7 * nc * sizeof(double) + sizeof(int)) {
        double* agg = ws;                       // 4*nc doubles
        double* car = ws + 4 * (size_t)nc;      // 3*nc doubles
        int* counter = (int*)(ws + 7 * (size_t)nc);
        hipMemsetAsync(counter, 0, sizeof(int), stream);   // graph-capture legal
        rs_phase12<16, 4, 12><<<nc, THREADS, 0, stream>>>(in, agg, car, counter, nc);
        rs_phase3<16, 4><<<nc, THREADS, 0, stream>>>(in, out, car, nc);
    } else {
        const int nc64 = n / 16384;
        double* agg = ws;
        double* car = ws + 4 * (size_t)nc64;
        int* counter = (int*)(ws + 7 * (size_t)nc64);
        hipMemsetAsync(counter, 0, sizeof(int), stream);
        rs_phase12<64, 6, 14><<<nc64, THREADS, 0, stream>>>(in, agg, car, counter, nc64);
        rs_phase3<64, 6><<<nc64, THREADS, 0, stream>>>(in, out, car, nc64);
    }
}

// Round 8
// 85.555 us; speedup vs baseline: 1.7318x; 1.7318x over previous
//
#include <hip/hip_runtime.h>
#include <math.h>

#define THREADS 256
#define GAMMA 0.99

typedef float vf4 __attribute__((ext_vector_type(4)));   // native vector for nontemporal store

// ---------- block-wide exclusive scan of linear transforms x -> g*x + v ----------
template<int NW>
__device__ __forceinline__ void block_compose_excl(int tid, double g, double v,
                                                   double& eg, double& ev,
                                                   double* lg, double* lv) {
    const int lane = tid & 63, wave = tid >> 6;
    double ig = g, iv = v;
#pragma unroll
    for (int k = 1; k < 64; k <<= 1) {
        double og = __shfl_up(ig, k);
        double ov = __shfl_up(iv, k);
        if (lane >= k) { iv = fma(ig, ov, iv); ig *= og; }
    }
    double weg = __shfl_up(ig, 1);
    double wev = __shfl_up(iv, 1);
    if (lane == 0) { weg = 1.0; wev = 0.0; }
    if (lane == 63) { lg[wave] = ig; lv[wave] = iv; }
    __syncthreads();
    double bg = 1.0, bv = 0.0;
    for (int w = 0; w < wave; ++w) { bv = fma(lg[w], bv, lv[w]); bg *= lg[w]; }
    eg = weg * bg;
    ev = fma(weg, bv, wev);
}

// ---------- block-wide exclusive additive scan of a pair ----------
template<int NW>
__device__ __forceinline__ void block_add_excl2(int tid, double a, double b,
                                                double& ea, double& eb,
                                                double* la, double* lb) {
    const int lane = tid & 63, wave = tid >> 6;
    double ia = a, ib = b;
#pragma unroll
    for (int k = 1; k < 64; k <<= 1) {
        double oa = __shfl_up(ia, k);
        double ob = __shfl_up(ib, k);
        if (lane >= k) { ia += oa; ib += ob; }
    }
    double wea = __shfl_up(ia, 1);
    double web = __shfl_up(ib, 1);
    if (lane == 0) { wea = 0.0; web = 0.0; }
    if (lane == 63) { la[wave] = ia; lb[wave] = ib; }
    __syncthreads();
    double ba = 0.0, bb = 0.0;
    for (int w = 0; w < wave; ++w) { ba += la[w]; bb += lb[w]; }
    ea = wea + ba;
    eb = web + bb;
}

// ---------- Phase 1: per-chunk zero-init aggregates, AoS agg[c*4+{A,Ps,Pq,P2}] ----------
template<int PT, int LPT>
__global__ __launch_bounds__(THREADS) void rs_phase1(const float* __restrict__ in,
                                                     double* __restrict__ agg, int nchunk) {
    constexpr int CHUNKE = THREADS * PT;
    __shared__ double lg[4], lv[4], r1[4], r2[4], r3[4];
    const int tid = threadIdx.x, lane = tid & 63, wave = tid >> 6;
    const int chunk = blockIdx.x;
    const float* src = in + (size_t)chunk * CHUNKE + (size_t)tid * PT;

    float rv[PT];
#pragma unroll
    for (int q = 0; q < PT / 4; ++q) {
        const float4 t = ((const float4*)src)[q];
        rv[4 * q] = t.x; rv[4 * q + 1] = t.y; rv[4 * q + 2] = t.z; rv[4 * q + 3] = t.w;
    }
    const float gf = (float)GAMMA;
    float p = 0.f, psum = 0.f, pq = 0.f, p2 = 0.f, gp = 1.f;
#pragma unroll
    for (int j = 0; j < PT; ++j) {
        p = fmaf(gf, p, rv[j]);
        gp *= gf;
        psum += p;
        pq = fmaf(gp, p, pq);
        p2 = fmaf(p, p, p2);
    }
    const double g = GAMMA;
    double gPT = g;
#pragma unroll
    for (int e = 0; e < LPT; ++e) gPT *= gPT;   // g^PT

    double eg, ev;
    block_compose_excl<4>(tid, gPT, (double)p, eg, ev, lg, lv);
    const double rho = ev, gexc = eg;

    const double G1 = g * (1.0 - gPT) / (1.0 - g);
    const double G2 = g * g * (1.0 - gPT * gPT) / (1.0 - g * g);
    double c1 = fma(rho, G1, (double)psum);
    double c2 = gexc * fma(rho, G2, (double)pq);
    double c3 = fma(rho * rho, G2, fma(2.0 * rho, (double)pq, (double)p2));
#pragma unroll
    for (int k = 32; k > 0; k >>= 1) {
        c1 += __shfl_down(c1, k);
        c2 += __shfl_down(c2, k);
        c3 += __shfl_down(c3, k);
    }
    if (lane == 0) { r1[wave] = c1; r2[wave] = c2; r3[wave] = c3; }
    __syncthreads();
    if (tid == 0) {
        double A = 0.0;
#pragma unroll
        for (int w = 0; w < 4; ++w) A = fma(lg[w], A, lv[w]);
        agg[4 * (size_t)chunk + 0] = A;
        agg[4 * (size_t)chunk + 1] = r1[0] + r1[1] + r1[2] + r1[3];
        agg[4 * (size_t)chunk + 2] = r2[0] + r2[1] + r2[2] + r2[3];
        agg[4 * (size_t)chunk + 3] = r3[0] + r3[1] + r3[2] + r3[3];
    }
}

// ---------- Phase 2: scan chunk carries; car[c*3+{Rin,S1C,S2C}] ----------
template<int CPT, int LOG2CHUNK>
__global__ __launch_bounds__(1024) void rs_phase2(const double* __restrict__ agg,
                                                  double* __restrict__ car, int nchunk) {
    __shared__ double lg[16], lv[16], la[16], lb[16];
    const int t = threadIdx.x;
    const double g = GAMMA;
    double gC = g;
#pragma unroll
    for (int e = 0; e < LOG2CHUNK; ++e) gC *= gC;   // g^CHUNKE

    double A[CPT], Ps[CPT], Pq[CPT], P2[CPT];
    const int c0 = t * CPT;
#pragma unroll
    for (int i = 0; i < CPT; ++i) {
        const int c = c0 + i;
        const bool ok = c < nchunk;
        A[i]  = ok ? agg[4 * (size_t)c + 0] : 0.0;
        Ps[i] = ok ? agg[4 * (size_t)c + 1] : 0.0;
        Pq[i] = ok ? agg[4 * (size_t)c + 2] : 0.0;
        P2[i] = ok ? agg[4 * (size_t)c + 3] : 0.0;
    }
    double mg = 1.0, mv = 0.0;
#pragma unroll
    for (int i = 0; i < CPT; ++i) { mv = fma(gC, mv, A[i]); mg *= gC; }

    double eg, ev;
    block_compose_excl<16>(t, mg, mv, eg, ev, lg, lv);

    const double G1C = g * (1.0 - gC) / (1.0 - g);
    const double G2C = g * g * (1.0 - gC * gC) / (1.0 - g * g);
    double Rin[CPT + 1];
    Rin[0] = ev;
    double s1[CPT], s2[CPT];
#pragma unroll
    for (int i = 0; i < CPT; ++i) {
        s1[i] = fma(Rin[i], G1C, Ps[i]);
        s2[i] = fma(Rin[i] * Rin[i], G2C, fma(2.0 * Rin[i], Pq[i], P2[i]));
        Rin[i + 1] = fma(gC, Rin[i], A[i]);
    }
    double ts1 = 0.0, ts2 = 0.0;
#pragma unroll
    for (int i = 0; i < CPT; ++i) { ts1 += s1[i]; ts2 += s2[i]; }
    double ea, eb;
    block_add_excl2<16>(t, ts1, ts2, ea, eb, la, lb);
#pragma unroll
    for (int i = 0; i < CPT; ++i) {
        const int c = c0 + i;
        if (c < nchunk) {
            car[3 * (size_t)c + 0] = Rin[i];
            car[3 * (size_t)c + 1] = ea;
            car[3 * (size_t)c + 2] = eb;
        }
        ea += s1[i];
        eb += s2[i];
    }
}

// ---------- Phase 3: rebase with true carries, emit scaled rewards ----------
// Register-only epilogue: no LDS output staging. Per-thread contiguous float4
// stores at 64B lane stride merge in L2 write-combining (same lines touched
// back-to-back by the wave's 4 store instructions).
template<int PT, int LPT>
__global__ __launch_bounds__(THREADS) void rs_phase3(const float* __restrict__ in,
                                                     float* __restrict__ out,
                                                     const double* __restrict__ car, int nchunk) {
    constexpr int CHUNKE = THREADS * PT;
    __shared__ double lg[4], lv[4], la[4], lb[4];
    const int tid = threadIdx.x;
    const int chunk = blockIdx.x;
    const float* src = in + (size_t)chunk * CHUNKE + (size_t)tid * PT;

    float rv[PT];
#pragma unroll
    for (int q = 0; q < PT / 4; ++q) {
        const float4 t = ((const float4*)src)[q];
        rv[4 * q] = t.x; rv[4 * q + 1] = t.y; rv[4 * q + 2] = t.z; rv[4 * q + 3] = t.w;
    }
    const float gf = (float)GAMMA;
    float p = 0.f, psum = 0.f, pq = 0.f, p2 = 0.f, gp = 1.f;
#pragma unroll
    for (int j = 0; j < PT; ++j) {
        p = fmaf(gf, p, rv[j]);
        gp *= gf;
        psum += p;
        pq = fmaf(gp, p, pq);
        p2 = fmaf(p, p, p2);
    }
    const double g = GAMMA;
    double gPT = g;
#pragma unroll
    for (int e = 0; e < LPT; ++e) gPT *= gPT;

    double eg, ev;
    block_compose_excl<4>(tid, gPT, (double)p, eg, ev, lg, lv);

    const double RinC = car[3 * (size_t)chunk + 0];
    const double S1C  = car[3 * (size_t)chunk + 1];
    const double S2C  = car[3 * (size_t)chunk + 2];
    const double rin  = fma(eg, RinC, ev);      // true incoming R for this thread's segment

    const double G1 = g * (1.0 - gPT) / (1.0 - g);
    const double G2 = g * g * (1.0 - gPT * gPT) / (1.0 - g * g);
    const double s1 = fma(rin, G1, (double)psum);
    const double s2 = fma(rin * rin, G2, fma(2.0 * rin, (double)pq, (double)p2));
    double ea, eb;
    block_add_excl2<4>(tid, s1, s2, ea, eb, la, lb);
    const double S1b = S1C + ea;
    const double S2b = S2C + eb;

    float ov[PT];

    if (chunk == 0) {
        // precise f64 epilogue for the small-cnt region (cancellation-sensitive)
        double R = rin, S1 = S1b, S2 = S2b;
        const size_t gbase = (size_t)tid * PT;
        for (int j = 0; j < PT; ++j) {
            const float rf = rv[j];
            R = fma(g, R, (double)rf);
            S1 += R;
            S2 = fma(R, R, S2);
            if (gbase + j == 0) {
                ov[j] = rf;                      // cnt < 2 -> std = 1
            } else {
                const double cnt = (double)(gbase + j + 1);
                const double inv = 1.0 / cnt;
                const double mean = S1 * inv;
                double var = fma(S2, inv, -(mean * mean));
                var = var > 0.0 ? var : 0.0;
                double sd = sqrt(var);
                sd = sd > 1e-8 ? sd : 1e-8;
                ov[j] = (float)((double)rf / sd);
            }
        }
    } else {
        // cnt >= CHUNKE+1: var*cnt^2 = S2*cnt - S1^2 has no cancellation ->
        // out = rf * cnt * rsqrt(S2*cnt - S1^2). One v_rsq replaces 2 divs + sqrt.
        float R = (float)rin;
        float ls1 = 0.f, ls2 = 0.f;
        const float S1bf = (float)S1b, S2bf = (float)S2b;
        const float base_cnt = (float)((size_t)chunk * CHUNKE + (size_t)tid * PT);
#pragma unroll
        for (int j = 0; j < PT; ++j) {
            const float rf = rv[j];
            R = fmaf(gf, R, rf);
            ls1 += R;
            ls2 = fmaf(R, R, ls2);
            const float cnt = base_cnt + (float)(j + 1);
            const float S1f = S1bf + ls1;
            const float S2f = S2bf + ls2;
            float t = fmaf(S2f, cnt, -(S1f * S1f));
            t = fmaxf(t, 1e-12f);
            ov[j] = rf * cnt * __builtin_amdgcn_rsqf(t);
        }
    }

    float* dst = out + (size_t)chunk * CHUNKE + (size_t)tid * PT;
#pragma unroll
    for (int q = 0; q < PT / 4; ++q) {
        vf4 v;
        v.x = ov[4 * q]; v.y = ov[4 * q + 1]; v.z = ov[4 * q + 2]; v.w = ov[4 * q + 3];
        __builtin_nontemporal_store(v, (vf4*)(dst) + q);   // don't evict L3-resident input
    }
}

extern "C" void kernel_launch(void* const* d_in, const int* in_sizes, int n_in,
                              void* d_out, int out_size, void* d_ws, size_t ws_size,
                              hipStream_t stream) {
    (void)n_in; (void)out_size;
    const float* in = (const float*)d_in[0];
    float* out = (float*)d_out;
    double* ws = (double*)d_ws;
    const int n = in_sizes[0];

    const int nc = n / 4096;
    if ((n % 4096) == 0 && nc >= 1 && nc <= 4096 &&
        ws_size >= (size_t)7 * nc * sizeof(double)) {
        double* agg = ws;                       // 4*nc doubles
        double* car = ws + 4 * (size_t)nc;      // 3*nc doubles
        rs_phase1<16, 4><<<nc, THREADS, 0, stream>>>(in, agg, nc);
        rs_phase2<4, 12><<<1, 1024, 0, stream>>>(agg, car, nc);
        rs_phase3<16, 4><<<nc, THREADS, 0, stream>>>(in, out, car, nc);
    } else {
        const int nc64 = n / 16384;
        double* agg = ws;
        double* car = ws + 4 * (size_t)nc64;
        rs_phase1<64, 6><<<nc64, THREADS, 0, stream>>>(in, agg, nc64);
        rs_phase2<4, 14><<<1, 1024, 0, stream>>>(agg, car, nc64);
        rs_phase3<64, 6><<<nc64, THREADS, 0, stream>>>(in, out, car, nc64);
    }
}

// Round 9
// 51.468 us; speedup vs baseline: 2.8788x; 1.6623x over previous
//
#include <hip/hip_runtime.h>
#include <math.h>

#define THREADS 256
#define GAMMA 0.99

typedef float vf4 __attribute__((ext_vector_type(4)));   // native vector for nontemporal store

// ---------- padded LDS index: stride PT+1 per thread (odd) -> 2-way banks (free) ----------
template<int LPT>
__device__ __forceinline__ int padi(int i) { return i + (i >> LPT); }

// ---------- block-wide exclusive scan of linear transforms x -> g*x + v (f64) ----------
template<int NW>
__device__ __forceinline__ void block_compose_excl(int tid, double g, double v,
                                                   double& eg, double& ev,
                                                   double* lg, double* lv) {
    const int lane = tid & 63, wave = tid >> 6;
    double ig = g, iv = v;
#pragma unroll
    for (int k = 1; k < 64; k <<= 1) {
        double og = __shfl_up(ig, k);
        double ov = __shfl_up(iv, k);
        if (lane >= k) { iv = fma(ig, ov, iv); ig *= og; }
    }
    double weg = __shfl_up(ig, 1);
    double wev = __shfl_up(iv, 1);
    if (lane == 0) { weg = 1.0; wev = 0.0; }
    if (lane == 63) { lg[wave] = ig; lv[wave] = iv; }
    __syncthreads();
    double bg = 1.0, bv = 0.0;
    for (int w = 0; w < wave; ++w) { bv = fma(lg[w], bv, lv[w]); bg *= lg[w]; }
    eg = weg * bg;
    ev = fma(weg, bv, wev);
}

// ---------- f32 variant (chunks >= 1: values O(1e3), f32 ample; underflow of g^k harmless) ----------
template<int NW>
__device__ __forceinline__ void block_compose_excl_f32(int tid, float g, float v,
                                                       float& eg, float& ev,
                                                       float* lg, float* lv) {
    const int lane = tid & 63, wave = tid >> 6;
    float ig = g, iv = v;
#pragma unroll
    for (int k = 1; k < 64; k <<= 1) {
        float og = __shfl_up(ig, k);
        float ov = __shfl_up(iv, k);
        if (lane >= k) { iv = fmaf(ig, ov, iv); ig *= og; }
    }
    float weg = __shfl_up(ig, 1);
    float wev = __shfl_up(iv, 1);
    if (lane == 0) { weg = 1.f; wev = 0.f; }
    if (lane == 63) { lg[wave] = ig; lv[wave] = iv; }
    __syncthreads();
    float bg = 1.f, bv = 0.f;
    for (int w = 0; w < wave; ++w) { bv = fmaf(lg[w], bv, lv[w]); bg *= lg[w]; }
    eg = weg * bg;
    ev = fmaf(weg, bv, wev);
}

// ---------- block-wide exclusive additive scan of a pair (f64) ----------
template<int NW>
__device__ __forceinline__ void block_add_excl2(int tid, double a, double b,
                                                double& ea, double& eb,
                                                double* la, double* lb) {
    const int lane = tid & 63, wave = tid >> 6;
    double ia = a, ib = b;
#pragma unroll
    for (int k = 1; k < 64; k <<= 1) {
        double oa = __shfl_up(ia, k);
        double ob = __shfl_up(ib, k);
        if (lane >= k) { ia += oa; ib += ob; }
    }
    double wea = __shfl_up(ia, 1);
    double web = __shfl_up(ib, 1);
    if (lane == 0) { wea = 0.0; web = 0.0; }
    if (lane == 63) { la[wave] = ia; lb[wave] = ib; }
    __syncthreads();
    double ba = 0.0, bb = 0.0;
    for (int w = 0; w < wave; ++w) { ba += la[w]; bb += lb[w]; }
    ea = wea + ba;
    eb = web + bb;
}

// ---------- f32 variant ----------
template<int NW>
__device__ __forceinline__ void block_add_excl2_f32(int tid, float a, float b,
                                                    float& ea, float& eb,
                                                    float* la, float* lb) {
    const int lane = tid & 63, wave = tid >> 6;
    float ia = a, ib = b;
#pragma unroll
    for (int k = 1; k < 64; k <<= 1) {
        float oa = __shfl_up(ia, k);
        float ob = __shfl_up(ib, k);
        if (lane >= k) { ia += oa; ib += ob; }
    }
    float wea = __shfl_up(ia, 1);
    float web = __shfl_up(ib, 1);
    if (lane == 0) { wea = 0.f; web = 0.f; }
    if (lane == 63) { la[wave] = ia; lb[wave] = ib; }
    __syncthreads();
    float ba = 0.f, bb = 0.f;
    for (int w = 0; w < wave; ++w) { ba += la[w]; bb += lb[w]; }
    ea = wea + ba;
    eb = web + bb;
}

// ---------- Phase 1: per-chunk zero-init aggregates, AoS agg[c*4+{A,Ps,Pq,P2}] ----------
template<int PT, int LPT>
__global__ __launch_bounds__(THREADS) void rs_phase1(const float* __restrict__ in,
                                                     double* __restrict__ agg, int nchunk) {
    constexpr int CHUNKE = THREADS * PT;
    __shared__ float flg[4], flv[4], r1[4], r2[4], r3[4];
    const int tid = threadIdx.x, lane = tid & 63, wave = tid >> 6;
    const int chunk = blockIdx.x;
    const float* src = in + (size_t)chunk * CHUNKE + (size_t)tid * PT;

    float rv[PT];
#pragma unroll
    for (int q = 0; q < PT / 4; ++q) {
        const float4 t = ((const float4*)src)[q];
        rv[4 * q] = t.x; rv[4 * q + 1] = t.y; rv[4 * q + 2] = t.z; rv[4 * q + 3] = t.w;
    }
    const float gf = (float)GAMMA;
    float p = 0.f, psum = 0.f, pq = 0.f, p2 = 0.f, gp = 1.f;
#pragma unroll
    for (int j = 0; j < PT; ++j) {
        p = fmaf(gf, p, rv[j]);
        gp *= gf;
        psum += p;
        pq = fmaf(gp, p, pq);
        p2 = fmaf(p, p, p2);
    }
    const double g = GAMMA;
    double gPT = g;
#pragma unroll
    for (int e = 0; e < LPT; ++e) gPT *= gPT;   // g^PT

    float egf, evf;
    block_compose_excl_f32<4>(tid, (float)gPT, p, egf, evf, flg, flv);
    const float rho = evf, gexc = egf;

    const float G1f = (float)(g * (1.0 - gPT) / (1.0 - g));
    const float G2f = (float)(g * g * (1.0 - gPT * gPT) / (1.0 - g * g));
    float c1 = fmaf(rho, G1f, psum);
    float c2 = gexc * fmaf(rho, G2f, pq);
    float c3 = fmaf(rho * rho, G2f, fmaf(2.f * rho, pq, p2));
#pragma unroll
    for (int k = 32; k > 0; k >>= 1) {
        c1 += __shfl_down(c1, k);
        c2 += __shfl_down(c2, k);
        c3 += __shfl_down(c3, k);
    }
    if (lane == 0) { r1[wave] = c1; r2[wave] = c2; r3[wave] = c3; }
    __syncthreads();
    if (tid == 0) {
        float A = 0.f;
#pragma unroll
        for (int w = 0; w < 4; ++w) A = fmaf(flg[w], A, flv[w]);
        agg[4 * (size_t)chunk + 0] = (double)A;
        agg[4 * (size_t)chunk + 1] = (double)(r1[0] + r1[1] + r1[2] + r1[3]);
        agg[4 * (size_t)chunk + 2] = (double)(r2[0] + r2[1] + r2[2] + r2[3]);
        agg[4 * (size_t)chunk + 3] = (double)(r3[0] + r3[1] + r3[2] + r3[3]);
    }
}

// ---------- Phase 2: scan chunk carries (f64); car[c*3+{Rin,S1C,S2C}] ----------
template<int CPT, int LOG2CHUNK>
__global__ __launch_bounds__(1024) void rs_phase2(const double* __restrict__ agg,
                                                  double* __restrict__ car, int nchunk) {
    __shared__ double lg[16], lv[16], la[16], lb[16];
    const int t = threadIdx.x;
    const double g = GAMMA;
    double gC = g;
#pragma unroll
    for (int e = 0; e < LOG2CHUNK; ++e) gC *= gC;   // g^CHUNKE

    double A[CPT], Ps[CPT], Pq[CPT], P2[CPT];
    const int c0 = t * CPT;
#pragma unroll
    for (int i = 0; i < CPT; ++i) {
        const int c = c0 + i;
        const bool ok = c < nchunk;
        A[i]  = ok ? agg[4 * (size_t)c + 0] : 0.0;
        Ps[i] = ok ? agg[4 * (size_t)c + 1] : 0.0;
        Pq[i] = ok ? agg[4 * (size_t)c + 2] : 0.0;
        P2[i] = ok ? agg[4 * (size_t)c + 3] : 0.0;
    }
    double mg = 1.0, mv = 0.0;
#pragma unroll
    for (int i = 0; i < CPT; ++i) { mv = fma(gC, mv, A[i]); mg *= gC; }

    double eg, ev;
    block_compose_excl<16>(t, mg, mv, eg, ev, lg, lv);

    const double G1C = g * (1.0 - gC) / (1.0 - g);
    const double G2C = g * g * (1.0 - gC * gC) / (1.0 - g * g);
    double Rin[CPT + 1];
    Rin[0] = ev;
    double s1[CPT], s2[CPT];
#pragma unroll
    for (int i = 0; i < CPT; ++i) {
        s1[i] = fma(Rin[i], G1C, Ps[i]);
        s2[i] = fma(Rin[i] * Rin[i], G2C, fma(2.0 * Rin[i], Pq[i], P2[i]));
        Rin[i + 1] = fma(gC, Rin[i], A[i]);
    }
    double ts1 = 0.0, ts2 = 0.0;
#pragma unroll
    for (int i = 0; i < CPT; ++i) { ts1 += s1[i]; ts2 += s2[i]; }
    double ea, eb;
    block_add_excl2<16>(t, ts1, ts2, ea, eb, la, lb);
#pragma unroll
    for (int i = 0; i < CPT; ++i) {
        const int c = c0 + i;
        if (c < nchunk) {
            car[3 * (size_t)c + 0] = Rin[i];
            car[3 * (size_t)c + 1] = ea;
            car[3 * (size_t)c + 2] = eb;
        }
        ea += s1[i];
        eb += s2[i];
    }
}

// ---------- Phase 3: rebase with true carries, emit scaled rewards ----------
// LDS-staged output: lane-contiguous nt stores (full-line coverage, no write amplification).
template<int PT, int LPT>
__global__ __launch_bounds__(THREADS) void rs_phase3(const float* __restrict__ in,
                                                     float* __restrict__ out,
                                                     const double* __restrict__ car, int nchunk) {
    constexpr int CHUNKE = THREADS * PT;
    __shared__ float sbuf[CHUNKE + THREADS];     // stride PT+1 per thread
    __shared__ double lg[4], lv[4], la[4], lb[4];
    __shared__ float flg[4], flv[4], fla[4], flb[4];
    const int tid = threadIdx.x;
    const int chunk = blockIdx.x;
    const float* src = in + (size_t)chunk * CHUNKE + (size_t)tid * PT;

    float rv[PT];
#pragma unroll
    for (int q = 0; q < PT / 4; ++q) {
        const float4 t = ((const float4*)src)[q];
        rv[4 * q] = t.x; rv[4 * q + 1] = t.y; rv[4 * q + 2] = t.z; rv[4 * q + 3] = t.w;
    }
    const float gf = (float)GAMMA;
    float p = 0.f, psum = 0.f, pq = 0.f, p2 = 0.f, gp = 1.f;
#pragma unroll
    for (int j = 0; j < PT; ++j) {
        p = fmaf(gf, p, rv[j]);
        gp *= gf;
        psum += p;
        pq = fmaf(gp, p, pq);
        p2 = fmaf(p, p, p2);
    }
    const double g = GAMMA;
    double gPT = g;
#pragma unroll
    for (int e = 0; e < LPT; ++e) gPT *= gPT;

    const double RinC = car[3 * (size_t)chunk + 0];
    const double S1C  = car[3 * (size_t)chunk + 1];
    const double S2C  = car[3 * (size_t)chunk + 2];

    const int a0 = padi<LPT>(tid * PT);          // = tid*(PT+1)

    if (chunk == 0) {
        // full f64 path for the small-cnt region (cancellation-sensitive)
        double eg, ev;
        block_compose_excl<4>(tid, gPT, (double)p, eg, ev, lg, lv);
        const double rin = fma(eg, RinC, ev);
        const double G1 = g * (1.0 - gPT) / (1.0 - g);
        const double G2 = g * g * (1.0 - gPT * gPT) / (1.0 - g * g);
        const double s1 = fma(rin, G1, (double)psum);
        const double s2 = fma(rin * rin, G2, fma(2.0 * rin, (double)pq, (double)p2));
        double ea, eb;
        block_add_excl2<4>(tid, s1, s2, ea, eb, la, lb);
        double R = rin, S1 = S1C + ea, S2 = S2C + eb;
        const size_t gbase = (size_t)tid * PT;
        for (int j = 0; j < PT; ++j) {
            const float rf = rv[j];
            R = fma(g, R, (double)rf);
            S1 += R;
            S2 = fma(R, R, S2);
            float ov;
            if (gbase + j == 0) {
                ov = rf;                         // cnt < 2 -> std = 1
            } else {
                const double cnt = (double)(gbase + j + 1);
                const double inv = 1.0 / cnt;
                const double mean = S1 * inv;
                double var = fma(S2, inv, -(mean * mean));
                var = var > 0.0 ? var : 0.0;
                double sd = sqrt(var);
                sd = sd > 1e-8 ? sd : 1e-8;
                ov = (float)((double)rf / sd);
            }
            sbuf[a0 + j] = ov;
        }
    } else {
        // f32 scans: values O(1e3), f32 ample; g^(64*tid) underflow harmless.
        float egf, evf;
        block_compose_excl_f32<4>(tid, (float)gPT, p, egf, evf, flg, flv);
        const float rin = fmaf(egf, (float)RinC, evf);
        const float G1f = (float)(g * (1.0 - gPT) / (1.0 - g));
        const float G2f = (float)(g * g * (1.0 - gPT * gPT) / (1.0 - g * g));
        const float s1f = fmaf(rin, G1f, psum);
        const float s2f = fmaf(rin * rin, G2f, fmaf(2.f * rin, pq, p2));
        float eaf, ebf;
        block_add_excl2_f32<4>(tid, s1f, s2f, eaf, ebf, fla, flb);
        const float S1bf = (float)S1C + eaf;
        const float S2bf = (float)S2C + ebf;

        // out = rf * cnt * rsqrt(S2*cnt - S1^2)  (no cancellation at cnt >= CHUNKE+1)
        float R = rin;
        float ls1 = 0.f, ls2 = 0.f;
        const float base_cnt = (float)((size_t)chunk * CHUNKE + (size_t)tid * PT);
#pragma unroll
        for (int j = 0; j < PT; ++j) {
            const float rf = rv[j];
            R = fmaf(gf, R, rf);
            ls1 += R;
            ls2 = fmaf(R, R, ls2);
            const float cnt = base_cnt + (float)(j + 1);
            const float S1f = S1bf + ls1;
            const float S2f = S2bf + ls2;
            float t = fmaf(S2f, cnt, -(S1f * S1f));
            t = fmaxf(t, 1e-12f);
            sbuf[a0 + j] = rf * cnt * __builtin_amdgcn_rsqf(t);
        }
    }
    __syncthreads();

    float* dst = out + (size_t)chunk * CHUNKE;
    for (int i = tid * 4; i < CHUNKE; i += THREADS * 4) {
        const int pp = padi<LPT>(i);
        vf4 v;
        v.x = sbuf[pp]; v.y = sbuf[pp + 1]; v.z = sbuf[pp + 2]; v.w = sbuf[pp + 3];
        __builtin_nontemporal_store(v, (vf4*)(dst + i));   // lane-contiguous: full-line nt stores
    }
}

extern "C" void kernel_launch(void* const* d_in, const int* in_sizes, int n_in,
                              void* d_out, int out_size, void* d_ws, size_t ws_size,
                              hipStream_t stream) {
    (void)n_in; (void)out_size;
    const float* in = (const float*)d_in[0];
    float* out = (float*)d_out;
    double* ws = (double*)d_ws;
    const int n = in_sizes[0];

    const int nc = n / 4096;
    if ((n % 4096) == 0 && nc >= 1 && nc <= 4096 &&
        ws_size >= (size_t)7 * nc * sizeof(double)) {
        double* agg = ws;                       // 4*nc doubles
        double* car = ws + 4 * (size_t)nc;      // 3*nc doubles
        rs_phase1<16, 4><<<nc, THREADS, 0, stream>>>(in, agg, nc);
        rs_phase2<4, 12><<<1, 1024, 0, stream>>>(agg, car, nc);
        rs_phase3<16, 4><<<nc, THREADS, 0, stream>>>(in, out, car, nc);
    } else {
        const int nc64 = n / 16384;
        double* agg = ws;
        double* car = ws + 4 * (size_t)nc64;
        rs_phase1<64, 6><<<nc64, THREADS, 0, stream>>>(in, agg, nc64);
        rs_phase2<4, 14><<<1, 1024, 0, stream>>>(agg, car, nc64);
        rs_phase3<64, 6><<<nc64, THREADS, 0, stream>>>(in, out, car, nc64);
    }
}